// Round 12
// baseline (54.515 us; speedup 1.0000x reference)
//
#include <hip/hip_runtime.h>

typedef __attribute__((ext_vector_type(8))) short short8;
typedef __attribute__((ext_vector_type(16))) float f32x16;
typedef __attribute__((ext_vector_type(2))) float f32x2;
typedef __attribute__((ext_vector_type(2))) unsigned int uint2v;
typedef __attribute__((ext_vector_type(4))) unsigned int uint4v;

#define HW 1026
#define CH_STRIDE (HW * HW)           /* 1052676 */
#define TW 32                         /* output cols per block     */
#define ROW_BYTES 1088                /* 34 px * 16ch * 2B         */
#define TILE_BYTES (18 * ROW_BYTES)   /* 19584; 2 bufs = 39168 -> 4 blocks/CU */

__device__ __forceinline__ unsigned short f2bf(float f) {
    unsigned int u = __builtin_bit_cast(unsigned int, f);
    u += 0x7fffu + ((u >> 16) & 1u);
    return (unsigned short)(u >> 16);
}

// stage NROWS input rows into buffer rows [R0, R0+NROWS); xrow0 = x-row of buffer row R0.
// layout: [row][px][16ch] bf16, 16B-half XOR swizzle. Values never cross a compute phase.
template<int R0, int NROWS>
__device__ __forceinline__ void stage_tile(const float* __restrict__ x, int xrow0, int w0,
                                           int tid, unsigned char* __restrict__ buf) {
    constexpr int UNITS  = 4 * NROWS * 17;         // 4ch x 2px units
    constexpr int ROUNDS = (UNITS + 255) / 256;
    f32x2 vals[ROUNDS][4];
    #pragma unroll
    for (int k = 0; k < ROUNDS; ++k) {             // issue all loads first
        const int idx = tid + k * 256;
        if (idx < UNITS) {
            const int c4  = idx / (NROWS * 17);
            const int rem = idx - c4 * (NROWS * 17);
            const int row = rem / 17;
            const int u   = rem - row * 17;
            const float* base = x + (4 * c4) * CH_STRIDE + (xrow0 + row) * HW + (w0 + 2 * u);
            #pragma unroll
            for (int j = 0; j < 4; ++j)
                vals[k][j] = *(const f32x2*)(base + j * CH_STRIDE);
        }
    }
    #pragma unroll
    for (int k = 0; k < ROUNDS; ++k) {             // then convert + ds_write
        const int idx = tid + k * 256;
        if (idx < UNITS) {
            const int c4  = idx / (NROWS * 17);
            const int rem = idx - c4 * (NROWS * 17);
            const int row = rem / 17;
            const int u   = rem - row * 17;
            #pragma unroll
            for (int p = 0; p < 2; ++p) {
                const int pp = 2 * u + p;
                const unsigned int lo  = (unsigned int)f2bf(vals[k][0][p]) |
                                         ((unsigned int)f2bf(vals[k][1][p]) << 16);
                const unsigned int hi2 = (unsigned int)f2bf(vals[k][2][p]) |
                                         ((unsigned int)f2bf(vals[k][3][p]) << 16);
                const int s16 = ((c4 >> 1) ^ (pp >> 2) ^ (pp >> 3)) & 1;
                const int off = (R0 + row) * ROW_BYTES + pp * 32 + s16 * 16 + (c4 & 1) * 8;
                uint2v t; t.x = lo; t.y = hi2;
                *(uint2v*)(buf + off) = t;
            }
        }
    }
}

// 16-row tile: 4 waves x 4 rows, 9 MFMAs each; plain coalesced stores (R9 win)
__device__ __forceinline__ void compute_store(const unsigned char* __restrict__ buf,
                                              const short8 (&af)[3][3],
                                              float* __restrict__ out,
                                              int h0, int w0, int wv, int n, int hi) {
    #pragma unroll
    for (int t = 0; t < 4; ++t) {
        const int baserow = wv * 4 + t;
        f32x16 acc;
        #pragma unroll
        for (int q = 0; q < 16; ++q) acc[q] = 0.0f;
        #pragma unroll
        for (int r = 0; r < 3; ++r) {
            #pragma unroll
            for (int s = 0; s < 3; ++s) {
                const int w   = n + s;
                const int s16 = (hi ^ (w >> 2) ^ (w >> 3)) & 1;
                const int off = (baserow + r) * ROW_BYTES + w * 32 + s16 * 16;
                const short8 bfr = *(const short8*)(buf + off);   // ds_read_b128
                acc = __builtin_amdgcn_mfma_f32_32x32x16_bf16(af[r][s], bfr, acc, 0, 0, 0);
            }
        }
        // C/D: col(lane&31)=pixel, row(q)=(q&3)+8*(q>>2)+4*hi = outch
        const int h = h0 + baserow;
        float* obase = out + (h << 10) + w0 + n;
        #pragma unroll
        for (int q = 0; q < 16; ++q) {
            const int o = (q & 3) + 8 * (q >> 2) + 4 * hi;
            obase[o << 20] = acc[q];
        }
    }
}

__global__ __launch_bounds__(256, 4)
void gck3x3_mfma_kernel(const float* __restrict__ x,
                        const float* __restrict__ kern,
                        float* __restrict__ out) {
    __shared__ __attribute__((aligned(16))) unsigned char s_x[2][TILE_BYTES];

    const int tid  = threadIdx.x;
    const int lane = tid & 63;
    const int wv   = tid >> 6;
    const int n    = lane & 31;
    const int hi   = lane >> 5;

    // XCD-aware bijective swizzle: 1024 = 8*128; vertical neighbors share an XCD L2
    const int bid = blockIdx.x;
    const int swz = (bid & 7) * 128 + (bid >> 3);
    const int h0  = (swz >> 5) * 32;   // 0..992 (block owns 32 rows)
    const int w0  = (swz & 31) * TW;   // 0..992

    // ---- tile A: x rows h0 .. h0+17 ----
    stage_tile<0, 18>(x, h0, w0, tid, &s_x[0][0]);

    // weight fragments (direct VMEM, L2-hot): W[o=n][c=8hi+j][r][s]
    short8 af[3][3];
    #pragma unroll
    for (int r = 0; r < 3; ++r) {
        #pragma unroll
        for (int s = 0; s < 3; ++s) {
            short8 v;
            #pragma unroll
            for (int j = 0; j < 8; ++j)
                v[j] = (short)f2bf(kern[n * 144 + (8 * hi + j) * 9 + r * 3 + s]);
            af[r][s] = v;
        }
    }
    __syncthreads();

    compute_store(&s_x[0][0], af, out, h0, w0, wv, n, hi);       // outputs h0..h0+15

    // ---- tile B: buffer rows 2..17 <- x rows h0+18..h0+33 (reads overlap A store drain) ----
    stage_tile<2, 16>(x, h0 + 18, w0, tid, &s_x[1][0]);
    // shared halo rows: B rows 0,1 copied LDS->LDS from A rows 16,17
    // (136 units of 16B <= 256 threads; swizzle is row-independent so raw copy is valid)
    if (tid < 136) {                       // 2 rows * 68 units of 16B
        const int row = tid / 68;
        const int k16 = tid - row * 68;
        *(uint4v*)(&s_x[1][0] + row * ROW_BYTES + k16 * 16) =
            *(const uint4v*)(&s_x[0][0] + (16 + row) * ROW_BYTES + k16 * 16);
    }
    __syncthreads();

    compute_store(&s_x[1][0], af, out, h0 + 16, w0, wv, n, hi);  // outputs h0+16..h0+31
}

extern "C" void kernel_launch(void* const* d_in, const int* in_sizes, int n_in,
                              void* d_out, int out_size, void* d_ws, size_t ws_size,
                              hipStream_t stream) {
    (void)in_sizes; (void)n_in; (void)d_ws; (void)ws_size; (void)out_size;
    const float* x    = (const float*)d_in[0];
    const float* kern = (const float*)d_in[1];
    float*       out  = (float*)d_out;
    gck3x3_mfma_kernel<<<1024, 256, 0, stream>>>(x, kern, out);
}